// Round 2
// baseline (230.326 us; speedup 1.0000x reference)
//
#include <hip/hip_runtime.h>

// Layout facts (floats):
//   input  x: (2,4,4,4,1048576)  -> slice(b,i) base = b*67108864 + i*16777216
//   output  : (2, 4*262144, 64)  -> slice(b,i) base = b*67108864 + i*16777216
// float4 strides: batch 16777216, level 4194304.
//
// from_tb index maps (per-slice flat j as function of volume coords X,Y,Z):
//   i=0: j = Y*65536 + Z*256 + X
//   i=1: j = [(Z%4)*1024 + (Y>>2)*16 + (Z>>4)]*4096 + X*16 + ((Z>>2)&3)*4 + (Y&3)
//   i=2: j = (Z%16)*2^20 + (Y>>4)*2^16 + X*256 + (Z>>4)*16 + (Y&15)
//   i=3: j = ((Z%64)>>2)*2^20 + X*4096 + ((Z&3)*16+(Y>>6)*4+(Z>>6))*64 + (Y&63)
// downscale^i = (4^i)^3 box average (axis order preserved); tile = coord mod.
// final to_tb: u=(Z>>2)*4096+(Y>>2)*64+(X>>2); e=(X&3)*16+(Y&3)*4+(Z&3).
//
// Two dispatches:
//   K1: l0 permutation + l1/l2/l3 reductions (independent, co-scheduled).
//   K2: l1/l2/l3 broadcasts; l3 final combine folded into each l3 block.

__global__ __launch_bounds__(256) void k_stage1(const float* __restrict__ in,
                                                float* __restrict__ out,
                                                float* __restrict__ d1,
                                                float* __restrict__ d2,
                                                float* __restrict__ p3) {
    const int b = blockIdx.y;
    const int bx = blockIdx.x;
    const int tid = threadIdx.x;
    __shared__ float smem[16 * 260];
    const float4* in4 = (const float4*)in;

    if (bx < 4096) {
        // ---- level 0: pure permutation via LDS tile ----
        const int Y_hi = bx >> 6, Z_hi = bx & 63;
        float4* out4 = (float4*)out;
        const long in_b4 = (long)b * 16777216;
#pragma unroll
        for (int k = 0; k < 4; ++k) {
            int idx = k * 256 + tid;
            int r = idx >> 6;
            int col4 = idx & 63;
            int Y = Y_hi * 4 + (r >> 2), Z = Z_hi * 4 + (r & 3);
            float4 v = in4[in_b4 + (long)Y * 16384 + Z * 64 + col4];
            *(float4*)&smem[r * 260 + col4 * 4] = v;
        }
        __syncthreads();
        const long out_b4 = (long)b * 16777216 + (long)Z_hi * 65536 + Y_hi * 1024;
#pragma unroll
        for (int k = 0; k < 4; ++k) {
            int idx = k * 256 + tid;
            int X = ((idx >> 4) << 2) + ((tid >> 2) & 3);
            int row0 = (tid & 3) * 4;
            float4 v;
            v.x = smem[(row0 + 0) * 260 + X];
            v.y = smem[(row0 + 1) * 260 + X];
            v.z = smem[(row0 + 2) * 260 + X];
            v.w = smem[(row0 + 3) * 260 + X];
            out4[out_b4 + idx] = v;
        }
    } else if (bx < 5120) {
        // ---- level 1 reduce: D1[64][64][64] per batch ----
        const int tlow = bx - 4096;   // 0..1023 = y'*16 + z'/4
        const long base4 = (long)b * 16777216 + 4194304;
        float acc[4] = {0.f, 0.f, 0.f, 0.f};
        for (int dz = 0; dz < 4; ++dz) {
            long rb = base4 + (long)(dz * 1024 + tlow) * 1024;
#pragma unroll
            for (int k = 0; k < 4; ++k) {
                float4 v = in4[rb + k * 256 + tid];
                acc[k] += v.x + v.y + v.z + v.w;
            }
        }
#pragma unroll
        for (int k = 0; k < 4; ++k) {
            acc[k] += __shfl_xor(acc[k], 4);
            acc[k] += __shfl_xor(acc[k], 8);
        }
        if ((tid & 12) == 0) {
            int yp = tlow >> 4;
            int zp = ((tlow & 15) << 2) + (tid & 3);
#pragma unroll
            for (int k = 0; k < 4; ++k) {
                int xp = k * 16 + (tid >> 4);
                d1[b * 262144 + xp * 4096 + yp * 64 + zp] = acc[k] * (1.0f / 64.0f);
            }
        }
    } else if (bx < 5376) {
        // ---- level 2 reduce: D2[16][16][16] per batch ----
        const int blk = bx - 5120;
        const int yp = blk >> 4, xp = blk & 15;
        const long base4 = (long)b * 16777216 + 2 * 4194304 + yp * 16384 + xp * 1024;
        float acc = 0.f;
        for (int dz = 0; dz < 16; ++dz) {
            long rb = base4 + (long)dz * 262144;
#pragma unroll
            for (int k = 0; k < 4; ++k) {
                float4 v = in4[rb + k * 256 + tid];
                acc += v.x + v.y + v.z + v.w;
            }
        }
        acc += __shfl_xor(acc, 1);
        acc += __shfl_xor(acc, 2);
        float* red = smem;   // 64 floats
        if ((tid & 3) == 0) red[tid >> 2] = acc;
        __syncthreads();
        if (tid < 16) {
            float s = red[tid] + red[16 + tid] + red[32 + tid] + red[48 + tid];
            d2[b * 4096 + xp * 256 + yp * 16 + tid] = s * (1.0f / 4096.0f);
        }
    } else {
        // ---- level 3 reduce partials ----
        const int blk = bx - 5376;                  // x'(2b) hi(4b) dxg(2b)
        const int xp = blk >> 6, hi = (blk >> 2) & 15, dxg = blk & 3;
        const long base4 = (long)b * 16777216 + 3 * 4194304 +
                           (long)hi * 262144 + xp * 65536 + dxg * 16384;
        float acc = 0.f;   // c = tid>>4 fixed per thread
        for (int k = 0; k < 64; ++k) {
            float4 v = in4[base4 + k * 256 + tid];
            acc += v.x + v.y + v.z + v.w;
        }
        acc += __shfl_xor(acc, 1);
        acc += __shfl_xor(acc, 2);
        acc += __shfl_xor(acc, 4);
        acc += __shfl_xor(acc, 8);
        float* red = smem;   // 16 floats
        if ((tid & 15) == 0) red[tid >> 4] = acc;
        __syncthreads();
        if (tid < 16)
            p3[((b * 4 + xp) * 64 + (blk & 63)) * 16 + tid] = red[tid];
    }
}

__global__ __launch_bounds__(256) void k_stage2(const float* __restrict__ d1,
                                                const float* __restrict__ d2,
                                                const float* __restrict__ p3,
                                                float* __restrict__ out) {
    const int b = blockIdx.y;
    const int bx = blockIdx.x;
    const int tid = threadIdx.x;
    __shared__ float4 smem4[1024];   // 16 KB; reused per path
    float4* out4 = (float4*)out;

    if (bx < 4096) {
        // ---- level 1 broadcast (table 1MB/batch, L2-resident) ----
        const float4* d14 = (const float4*)d1;
        const long ob = (long)b * 16777216 + 4194304;
        const int d1b = b * 65536;
#pragma unroll
        for (int k = 0; k < 4; ++k) {
            int o4 = bx * 1024 + k * 256 + tid;
            int u = o4 >> 4;
            int Xl = (o4 >> 2) & 3, Yl = o4 & 3;
            int Xh = u & 63, Yh = (u >> 6) & 63, Zh = u >> 12;
            int x = (Xh & 15) * 4 + Xl, y = (Yh & 15) * 4 + Yl;
            out4[ob + o4] = d14[d1b + x * 1024 + y * 16 + (Zh & 15)];
        }
    } else if (bx < 8192) {
        // ---- level 2 broadcast (table 16KB -> LDS) ----
        const int blk = bx - 4096;
        const float4* d24 = (const float4*)d2;
#pragma unroll
        for (int j = 0; j < 4; ++j) smem4[j * 256 + tid] = d24[b * 1024 + j * 256 + tid];
        __syncthreads();
        const long ob = (long)b * 16777216 + 2 * 4194304;
#pragma unroll
        for (int k = 0; k < 4; ++k) {
            int o4 = blk * 1024 + k * 256 + tid;
            int u = o4 >> 4;
            int Xl = (o4 >> 2) & 3, Yl = o4 & 3;
            int Xh = u & 63, Yh = (u >> 6) & 63, Zh = u >> 12;
            int x = (Xh & 3) * 4 + Xl, y = (Yh & 3) * 4 + Yl;
            out4[ob + o4] = smem4[x * 64 + y * 4 + (Zh & 3)];
        }
    } else {
        // ---- level 3: fold final combine (p3 is 32KB, L2-resident) + broadcast ----
        const int blk = bx - 8192;
        float* red = (float*)smem4;       // red[4][64] then tab[64] at +256
        float* tab = red + 256;
        int o = tid & 63, grp = tid >> 6;                 // o = xp*16 + c
        int xp = o >> 4, c = o & 15;
        const float* pb = p3 + (long)((b * 4 + xp) * 64) * 16 + c;
        float s = 0.f;
#pragma unroll
        for (int k = 0; k < 16; ++k) s += pb[(grp * 16 + k) * 16];
        red[grp * 64 + o] = s;
        __syncthreads();
        if (tid < 64)
            tab[tid] = (red[tid] + red[64 + tid] + red[128 + tid] + red[192 + tid])
                       * (1.0f / 262144.0f);
        __syncthreads();
        const float4 v = *(const float4*)&tab[(tid & 15) * 4];
        const long ob = (long)b * 16777216 + 3 * 4194304;
#pragma unroll
        for (int k = 0; k < 4; ++k)
            out4[ob + blk * 1024 + k * 256 + tid] = v;
    }
}

extern "C" void kernel_launch(void* const* d_in, const int* in_sizes, int n_in,
                              void* d_out, int out_size, void* d_ws, size_t ws_size,
                              hipStream_t stream) {
    const float* in = (const float*)d_in[0];
    float* out = (float*)d_out;
    float* ws = (float*)d_ws;
    float* d1 = ws;                          // 2*262144 floats (2 MB)
    float* d2 = ws + 524288;                 // 2*4096
    float* p3 = ws + 524288 + 8192;          // 2*4*64*16 = 8192
    k_stage1<<<dim3(5632, 2),  256, 0, stream>>>(in, out, d1, d2, p3);
    k_stage2<<<dim3(12288, 2), 256, 0, stream>>>(d1, d2, p3, out);
}

// Round 3
// 224.686 us; speedup vs baseline: 1.0251x; 1.0251x over previous
//
#include <hip/hip_runtime.h>

// Layout facts (floats):
//   input  x: (2,4,4,4,1048576)  -> slice(b,i) base = b*67108864 + i*16777216
//   output  : (2, 4*262144, 64)  -> slice(b,i) base = b*67108864 + i*16777216
// float4 strides: batch 16777216, level 4194304.
//
// from_tb index maps (per-slice flat j as function of volume coords X,Y,Z):
//   i=0: j = Y*65536 + Z*256 + X
//   i=1: j = [(Z%4)*1024 + (Y>>2)*16 + (Z>>4)]*4096 + X*16 + ((Z>>2)&3)*4 + (Y&3)
//   i=2: j = (Z%16)*2^20 + (Y>>4)*2^16 + X*256 + (Z>>4)*16 + (Y&15)
//   i=3: j = ((Z%64)>>2)*2^20 + X*4096 + ((Z&3)*16+(Y>>6)*4+(Z>>6))*64 + (Y&63)
// downscale^i = (4^i)^3 box average (axis order preserved); tile = coord mod.
// final to_tb: u=(Z>>2)*4096+(Y>>2)*64+(X>>2); e=(X&3)*16+(Y&3)*4+(Z&3).
//
// Three dispatches, uniform ~32KB-traffic blocks in stage1:
//   S1: perm(4096) | l1red k-split(2048) | l2red dz-split->p2(2048) | l3red k-split->p3(2048)
//   C : p2 -> d2 (8-way), p3 -> d3 (512-way)
//   S2: l1/l2/l3 broadcasts from final tables (uniform 16KB writes)

__global__ __launch_bounds__(256) void k_stage1(const float* __restrict__ in,
                                                float* __restrict__ out,
                                                float* __restrict__ d1,
                                                float* __restrict__ p2,
                                                float* __restrict__ p3) {
    const int b = blockIdx.y;
    const int bx = blockIdx.x;
    const int tid = threadIdx.x;
    __shared__ float smem[16 * 260];
    const float4* in4 = (const float4*)in;

    if (bx < 4096) {
        // ---- level 0: pure permutation via LDS tile (16KB R + 16KB W) ----
        const int Y_hi = bx >> 6, Z_hi = bx & 63;
        float4* out4 = (float4*)out;
        const long in_b4 = (long)b * 16777216;
#pragma unroll
        for (int k = 0; k < 4; ++k) {
            int idx = k * 256 + tid;
            int r = idx >> 6;
            int col4 = idx & 63;
            int Y = Y_hi * 4 + (r >> 2), Z = Z_hi * 4 + (r & 3);
            float4 v = in4[in_b4 + (long)Y * 16384 + Z * 64 + col4];
            *(float4*)&smem[r * 260 + col4 * 4] = v;
        }
        __syncthreads();
        const long out_b4 = (long)b * 16777216 + (long)Z_hi * 65536 + Y_hi * 1024;
#pragma unroll
        for (int k = 0; k < 4; ++k) {
            int idx = k * 256 + tid;
            int X = ((idx >> 4) << 2) + ((tid >> 2) & 3);
            int row0 = (tid & 3) * 4;
            float4 v;
            v.x = smem[(row0 + 0) * 260 + X];
            v.y = smem[(row0 + 1) * 260 + X];
            v.z = smem[(row0 + 2) * 260 + X];
            v.w = smem[(row0 + 3) * 260 + X];
            out4[out_b4 + idx] = v;
        }
    } else if (bx < 6144) {
        // ---- level 1 reduce, split by k-pair (32KB read, exact partition) ----
        const int blk = bx - 4096;           // 0..2047
        const int tlow = blk >> 1;           // y'*16 + z'/4
        const int kh = blk & 1;
        const long base4 = (long)b * 16777216 + 4194304;
        float acc[2] = {0.f, 0.f};
        for (int dz = 0; dz < 4; ++dz) {
            long rb = base4 + (long)(dz * 1024 + tlow) * 1024;
#pragma unroll
            for (int kk = 0; kk < 2; ++kk) {
                int k = kh * 2 + kk;
                float4 v = in4[rb + k * 256 + tid];
                acc[kk] += v.x + v.y + v.z + v.w;
            }
        }
#pragma unroll
        for (int kk = 0; kk < 2; ++kk) {     // reduce dx bits (tid 2..3)
            acc[kk] += __shfl_xor(acc[kk], 4);
            acc[kk] += __shfl_xor(acc[kk], 8);
        }
        if ((tid & 12) == 0) {
            int yp = tlow >> 4;
            int zp = ((tlow & 15) << 2) + (tid & 3);
#pragma unroll
            for (int kk = 0; kk < 2; ++kk) {
                int xp = (kh * 2 + kk) * 16 + (tid >> 4);
                d1[b * 262144 + xp * 4096 + yp * 64 + zp] = acc[kk] * (1.0f / 64.0f);
            }
        }
    } else if (bx < 8192) {
        // ---- level 2 reduce partials, dz split into 8 groups of 2 (32KB) ----
        const int blk = bx - 6144;           // 0..2047
        const int g = blk & 7, cell = blk >> 3;
        const int yp = cell >> 4, xp = cell & 15;
        const long base4 = (long)b * 16777216 + 2 * 4194304 + yp * 16384 + xp * 1024;
        float acc = 0.f;
        for (int dzi = 0; dzi < 2; ++dzi) {
            long rb = base4 + (long)(g * 2 + dzi) * 262144;
#pragma unroll
            for (int k = 0; k < 4; ++k) {
                float4 v = in4[rb + k * 256 + tid];  // z' = (tid>>2)&15
                acc += v.x + v.y + v.z + v.w;
            }
        }
        acc += __shfl_xor(acc, 1);
        acc += __shfl_xor(acc, 2);
        float* red = smem;   // 64 floats
        if ((tid & 3) == 0) red[tid >> 2] = acc;
        __syncthreads();
        if (tid < 16) {
            float s = red[tid] + red[16 + tid] + red[32 + tid] + red[48 + tid];
            p2[(b * 8 + g) * 4096 + xp * 256 + yp * 16 + tid] = s;
        }
    } else {
        // ---- level 3 reduce partials, k split into 8 chunks of 8 (32KB) ----
        const int blk = bx - 8192;           // 0..2047
        const int kc = blk & 7;
        const int orig = blk >> 3;           // x'(2b) hi(4b) dxg(2b)
        const int xp = orig >> 6, hi = (orig >> 2) & 15, dxg = orig & 3;
        const long base4 = (long)b * 16777216 + 3 * 4194304 +
                           (long)hi * 262144 + xp * 65536 + dxg * 16384;
        float acc = 0.f;                     // c = tid>>4 fixed per thread
        for (int kk = 0; kk < 8; ++kk) {
            float4 v = in4[base4 + (kc * 8 + kk) * 256 + tid];
            acc += v.x + v.y + v.z + v.w;
        }
        acc += __shfl_xor(acc, 1);
        acc += __shfl_xor(acc, 2);
        acc += __shfl_xor(acc, 4);
        acc += __shfl_xor(acc, 8);
        float* red = smem;   // 16 floats
        if ((tid & 15) == 0) red[tid >> 4] = acc;
        __syncthreads();
        if (tid < 16) {
            int G = (hi * 4 + dxg) * 8 + kc;             // 0..511
            p3[((b * 4 + xp) * 512 + G) * 16 + tid] = red[tid];
        }
    }
}

__global__ __launch_bounds__(256) void k_combine(const float* __restrict__ p2,
                                                 const float* __restrict__ p3,
                                                 float* __restrict__ d2,
                                                 float* __restrict__ d3) {
    const int bid = blockIdx.x;
    const int tid = threadIdx.x;
    if (bid < 32) {
        // d2: 8192 entries, 8-way partial sum
        int idx = bid * 256 + tid;
        int b = idx >> 12, r = idx & 4095;
        float s = 0.f;
#pragma unroll
        for (int g = 0; g < 8; ++g) s += p2[(b * 8 + g) * 4096 + r];
        d2[idx] = s * (1.0f / 4096.0f);
    } else {
        // d3: block per (b,xp); 16 lanes per c sum 32 groups each, LDS reduce
        int v = bid - 32;                    // 0..7
        int b = v >> 2, xp = v & 3;
        int c = tid & 15, gp = tid >> 4;     // 16 parts
        const float* pb = p3 + (long)((b * 4 + xp) * 512) * 16 + c;
        float s = 0.f;
#pragma unroll
        for (int j = 0; j < 32; ++j) s += pb[(gp * 32 + j) * 16];
        __shared__ float red[256];
        red[gp * 16 + c] = s;
        __syncthreads();
        if (tid < 16) {
            float t = 0.f;
#pragma unroll
            for (int g = 0; g < 16; ++g) t += red[g * 16 + tid];
            d3[b * 64 + xp * 16 + tid] = t * (1.0f / 262144.0f);
        }
    }
}

__global__ __launch_bounds__(256) void k_stage2(const float* __restrict__ d1,
                                                const float* __restrict__ d2,
                                                const float* __restrict__ d3,
                                                float* __restrict__ out) {
    const int b = blockIdx.y;
    const int bx = blockIdx.x;
    const int tid = threadIdx.x;
    __shared__ float4 smem4[1024];   // 16 KB; used by l2 path
    float4* out4 = (float4*)out;

    if (bx < 4096) {
        // ---- level 1 broadcast (table 1MB/batch, L2-resident) ----
        const float4* d14 = (const float4*)d1;
        const long ob = (long)b * 16777216 + 4194304;
        const int d1b = b * 65536;
#pragma unroll
        for (int k = 0; k < 4; ++k) {
            int o4 = bx * 1024 + k * 256 + tid;
            int u = o4 >> 4;
            int Xl = (o4 >> 2) & 3, Yl = o4 & 3;
            int Xh = u & 63, Yh = (u >> 6) & 63, Zh = u >> 12;
            int x = (Xh & 15) * 4 + Xl, y = (Yh & 15) * 4 + Yl;
            out4[ob + o4] = d14[d1b + x * 1024 + y * 16 + (Zh & 15)];
        }
    } else if (bx < 8192) {
        // ---- level 2 broadcast (table 16KB -> LDS) ----
        const int blk = bx - 4096;
        const float4* d24 = (const float4*)d2;
#pragma unroll
        for (int j = 0; j < 4; ++j) smem4[j * 256 + tid] = d24[b * 1024 + j * 256 + tid];
        __syncthreads();
        const long ob = (long)b * 16777216 + 2 * 4194304;
#pragma unroll
        for (int k = 0; k < 4; ++k) {
            int o4 = blk * 1024 + k * 256 + tid;
            int u = o4 >> 4;
            int Xl = (o4 >> 2) & 3, Yl = o4 & 3;
            int Xh = u & 63, Yh = (u >> 6) & 63, Zh = u >> 12;
            int x = (Xh & 3) * 4 + Xl, y = (Yh & 3) * 4 + Yl;
            out4[ob + o4] = smem4[x * 64 + y * 4 + (Zh & 3)];
        }
    } else {
        // ---- level 3 broadcast: same 64-float row everywhere ----
        const int blk = bx - 8192;
        const float4* d34 = (const float4*)d3;
        const float4 v = d34[b * 16 + (tid & 15)];
        const long ob = (long)b * 16777216 + 3 * 4194304;
#pragma unroll
        for (int k = 0; k < 4; ++k)
            out4[ob + blk * 1024 + k * 256 + tid] = v;
    }
}

extern "C" void kernel_launch(void* const* d_in, const int* in_sizes, int n_in,
                              void* d_out, int out_size, void* d_ws, size_t ws_size,
                              hipStream_t stream) {
    const float* in = (const float*)d_in[0];
    float* out = (float*)d_out;
    float* ws = (float*)d_ws;
    float* d1 = ws;                               // 2*262144 = 524288 floats
    float* p2 = ws + 524288;                      // 2*8*4096 = 65536
    float* p3 = ws + 524288 + 65536;              // 2*4*512*16 = 65536
    float* d2 = ws + 524288 + 65536 + 65536;      // 2*4096 = 8192
    float* d3 = ws + 524288 + 65536 + 65536 + 8192;  // 128
    k_stage1 <<<dim3(10240, 2), 256, 0, stream>>>(in, out, d1, p2, p3);
    k_combine<<<40, 256, 0, stream>>>(p2, p3, d2, d3);
    k_stage2 <<<dim3(12288, 2), 256, 0, stream>>>(d1, d2, d3, out);
}

// Round 4
// 187.145 us; speedup vs baseline: 1.2307x; 1.2006x over previous
//
#include <hip/hip_runtime.h>

// Layout facts (floats):
//   input  x: (2,4,4,4,1048576)  -> slice(b,i) base = b*67108864 + i*16777216
//   output  : (2, 4*262144, 64)  -> slice(b,i) base = b*67108864 + i*16777216
// float4 strides: batch 16777216, level 4194304.
//
// from_tb index maps (per-slice flat j as function of volume coords X,Y,Z):
//   i=0: j = Y*65536 + Z*256 + X
//   i=1: j = [(Z%4)*1024 + (Y>>2)*16 + (Z>>4)]*4096 + X*16 + ((Z>>2)&3)*4 + (Y&3)
//   i=2: j = (Z%16)*2^20 + (Y>>4)*2^16 + X*256 + (Z>>4)*16 + (Y&15)
//   i=3: j = ((Z%64)>>2)*2^20 + X*4096 + ((Z&3)*16+(Y>>6)*4+(Z>>6))*64 + (Y&63)
// downscale^i = (4^i)^3 box average (axis order preserved); tile = coord mod.
// final to_tb: u=(Z>>2)*4096+(Y>>2)*64+(X>>2); e=(X&3)*16+(Y&3)*4+(Z&3).
//
// Four direction-pure dispatches:
//   D1 k_reduce : l1/l2/l3 reductions, uniform 32KB pure-read blocks (384 MB)
//   D2 k_combine: partials -> d2, d3 (tiny)
//   D3 k_perm   : level-0 permutation (128R + 128W)
//   D4 k_bcast  : l1/l2/l3 broadcasts, uniform 16KB pure-write blocks (384 MB)
// NT loads on streamed input, NT stores on out (protect L2 table residency).

typedef float f4 __attribute__((ext_vector_type(4)));

__global__ __launch_bounds__(256) void k_reduce(const float* __restrict__ in,
                                                float* __restrict__ d1,
                                                float* __restrict__ p2,
                                                float* __restrict__ p3) {
    const int b = blockIdx.y;
    const int bx = blockIdx.x;
    const int tid = threadIdx.x;
    __shared__ float red[64];
    const f4* in4 = (const f4*)in;

    if (bx < 2048) {
        // ---- level 1 reduce, split by k-pair (32KB read, exact partition) ----
        const int tlow = bx >> 1;            // y'*16 + z'/4
        const int kh = bx & 1;
        const long base4 = (long)b * 16777216 + 4194304;
        float acc[2] = {0.f, 0.f};
        for (int dz = 0; dz < 4; ++dz) {
            long rb = base4 + (long)(dz * 1024 + tlow) * 1024;
#pragma unroll
            for (int kk = 0; kk < 2; ++kk) {
                f4 v = __builtin_nontemporal_load(&in4[rb + (kh * 2 + kk) * 256 + tid]);
                acc[kk] += v.x + v.y + v.z + v.w;
            }
        }
#pragma unroll
        for (int kk = 0; kk < 2; ++kk) {     // reduce dx bits (tid 2..3)
            acc[kk] += __shfl_xor(acc[kk], 4);
            acc[kk] += __shfl_xor(acc[kk], 8);
        }
        if ((tid & 12) == 0) {
            int yp = tlow >> 4;
            int zp = ((tlow & 15) << 2) + (tid & 3);
#pragma unroll
            for (int kk = 0; kk < 2; ++kk) {
                int xp = (kh * 2 + kk) * 16 + (tid >> 4);
                d1[b * 262144 + xp * 4096 + yp * 64 + zp] = acc[kk] * (1.0f / 64.0f);
            }
        }
    } else if (bx < 4096) {
        // ---- level 2 reduce partials, dz split into 8 groups of 2 (32KB) ----
        const int blk = bx - 2048;
        const int g = blk & 7, cell = blk >> 3;
        const int yp = cell >> 4, xp = cell & 15;
        const long base4 = (long)b * 16777216 + 2 * 4194304 + yp * 16384 + xp * 1024;
        float acc = 0.f;
        for (int dzi = 0; dzi < 2; ++dzi) {
            long rb = base4 + (long)(g * 2 + dzi) * 262144;
#pragma unroll
            for (int k = 0; k < 4; ++k) {
                f4 v = __builtin_nontemporal_load(&in4[rb + k * 256 + tid]);
                acc += v.x + v.y + v.z + v.w;   // z' = (tid>>2)&15
            }
        }
        acc += __shfl_xor(acc, 1);
        acc += __shfl_xor(acc, 2);
        if ((tid & 3) == 0) red[tid >> 2] = acc;
        __syncthreads();
        if (tid < 16) {
            float s = red[tid] + red[16 + tid] + red[32 + tid] + red[48 + tid];
            p2[(b * 8 + g) * 4096 + xp * 256 + yp * 16 + tid] = s;
        }
    } else {
        // ---- level 3 reduce partials, k split into 8 chunks of 8 (32KB) ----
        const int blk = bx - 4096;
        const int kc = blk & 7;
        const int orig = blk >> 3;           // x'(2b) hi(4b) dxg(2b)
        const int xp = orig >> 6, hi = (orig >> 2) & 15, dxg = orig & 3;
        const long base4 = (long)b * 16777216 + 3 * 4194304 +
                           (long)hi * 262144 + xp * 65536 + dxg * 16384;
        float acc = 0.f;                     // c = tid>>4 fixed per thread
        for (int kk = 0; kk < 8; ++kk) {
            f4 v = __builtin_nontemporal_load(&in4[base4 + (kc * 8 + kk) * 256 + tid]);
            acc += v.x + v.y + v.z + v.w;
        }
        acc += __shfl_xor(acc, 1);
        acc += __shfl_xor(acc, 2);
        acc += __shfl_xor(acc, 4);
        acc += __shfl_xor(acc, 8);
        if ((tid & 15) == 0) red[tid >> 4] = acc;
        __syncthreads();
        if (tid < 16) {
            int G = (hi * 4 + dxg) * 8 + kc;             // 0..511
            p3[((b * 4 + xp) * 512 + G) * 16 + tid] = red[tid];
        }
    }
}

__global__ __launch_bounds__(256) void k_combine(const float* __restrict__ p2,
                                                 const float* __restrict__ p3,
                                                 float* __restrict__ d2,
                                                 float* __restrict__ d3) {
    const int bid = blockIdx.x;
    const int tid = threadIdx.x;
    if (bid < 32) {
        // d2: 8192 entries, 8-way partial sum
        int idx = bid * 256 + tid;
        int b = idx >> 12, r = idx & 4095;
        float s = 0.f;
#pragma unroll
        for (int g = 0; g < 8; ++g) s += p2[(b * 8 + g) * 4096 + r];
        d2[idx] = s * (1.0f / 4096.0f);
    } else {
        // d3: block per (b,xp); 16 parts per c over 512 groups, LDS reduce
        int v = bid - 32;                    // 0..7
        int b = v >> 2, xp = v & 3;
        int c = tid & 15, gp = tid >> 4;
        const float* pb = p3 + (long)((b * 4 + xp) * 512) * 16 + c;
        float s = 0.f;
#pragma unroll
        for (int j = 0; j < 32; ++j) s += pb[(gp * 32 + j) * 16];
        __shared__ float red[256];
        red[gp * 16 + c] = s;
        __syncthreads();
        if (tid < 16) {
            float t = 0.f;
#pragma unroll
            for (int g = 0; g < 16; ++g) t += red[g * 16 + tid];
            d3[b * 64 + xp * 16 + tid] = t * (1.0f / 262144.0f);
        }
    }
}

__global__ __launch_bounds__(256) void k_perm(const float* __restrict__ in,
                                              float* __restrict__ out) {
    const int b = blockIdx.y;
    const int Y_hi = blockIdx.x >> 6, Z_hi = blockIdx.x & 63;
    const int tid = threadIdx.x;
    __shared__ float lds[16 * 260];
    const f4* in4 = (const f4*)in;
    f4* out4 = (f4*)out;
    const long in_b4 = (long)b * 16777216;
#pragma unroll
    for (int k = 0; k < 4; ++k) {
        int idx = k * 256 + tid;
        int r = idx >> 6;
        int col4 = idx & 63;
        int Y = Y_hi * 4 + (r >> 2), Z = Z_hi * 4 + (r & 3);
        f4 v = __builtin_nontemporal_load(&in4[in_b4 + (long)Y * 16384 + Z * 64 + col4]);
        *(f4*)&lds[r * 260 + col4 * 4] = v;
    }
    __syncthreads();
    const long out_b4 = (long)b * 16777216 + (long)Z_hi * 65536 + Y_hi * 1024;
#pragma unroll
    for (int k = 0; k < 4; ++k) {
        int idx = k * 256 + tid;
        int X = ((idx >> 4) << 2) + ((tid >> 2) & 3);
        int row0 = (tid & 3) * 4;
        f4 v;
        v.x = lds[(row0 + 0) * 260 + X];
        v.y = lds[(row0 + 1) * 260 + X];
        v.z = lds[(row0 + 2) * 260 + X];
        v.w = lds[(row0 + 3) * 260 + X];
        __builtin_nontemporal_store(v, &out4[out_b4 + idx]);
    }
}

__global__ __launch_bounds__(256) void k_bcast(const float* __restrict__ d1,
                                               const float* __restrict__ d2,
                                               const float* __restrict__ d3,
                                               float* __restrict__ out) {
    const int b = blockIdx.y;
    const int bx = blockIdx.x;
    const int tid = threadIdx.x;
    f4* out4 = (f4*)out;

    if (bx < 4096) {
        // ---- level 1 broadcast (table 1MB/batch, L2-resident) ----
        const f4* d14 = (const f4*)d1;
        const long ob = (long)b * 16777216 + 4194304;
        const int d1b = b * 65536;
#pragma unroll
        for (int k = 0; k < 4; ++k) {
            int o4 = bx * 1024 + k * 256 + tid;
            int u = o4 >> 4;
            int Xl = (o4 >> 2) & 3, Yl = o4 & 3;
            int Xh = u & 63, Yh = (u >> 6) & 63, Zh = u >> 12;
            int x = (Xh & 15) * 4 + Xl, y = (Yh & 15) * 4 + Yl;
            f4 v = d14[d1b + x * 1024 + y * 16 + (Zh & 15)];
            __builtin_nontemporal_store(v, &out4[ob + o4]);
        }
    } else if (bx < 8192) {
        // ---- level 2 broadcast (table 16KB/batch, L2-resident) ----
        const int blk = bx - 4096;
        const f4* d24 = (const f4*)d2;
        const long ob = (long)b * 16777216 + 2 * 4194304;
#pragma unroll
        for (int k = 0; k < 4; ++k) {
            int o4 = blk * 1024 + k * 256 + tid;
            int u = o4 >> 4;
            int Xl = (o4 >> 2) & 3, Yl = o4 & 3;
            int Xh = u & 63, Yh = (u >> 6) & 63, Zh = u >> 12;
            int x = (Xh & 3) * 4 + Xl, y = (Yh & 3) * 4 + Yl;
            f4 v = d24[b * 1024 + x * 64 + y * 4 + (Zh & 3)];
            __builtin_nontemporal_store(v, &out4[ob + o4]);
        }
    } else {
        // ---- level 3 broadcast: same 64-float row everywhere ----
        const int blk = bx - 8192;
        const f4* d34 = (const f4*)d3;
        const f4 v = d34[b * 16 + (tid & 15)];
        const long ob = (long)b * 16777216 + 3 * 4194304;
#pragma unroll
        for (int k = 0; k < 4; ++k)
            __builtin_nontemporal_store(v, &out4[ob + blk * 1024 + k * 256 + tid]);
    }
}

extern "C" void kernel_launch(void* const* d_in, const int* in_sizes, int n_in,
                              void* d_out, int out_size, void* d_ws, size_t ws_size,
                              hipStream_t stream) {
    const float* in = (const float*)d_in[0];
    float* out = (float*)d_out;
    float* ws = (float*)d_ws;
    float* d1 = ws;                               // 2*262144 = 524288 floats
    float* p2 = ws + 524288;                      // 2*8*4096 = 65536
    float* p3 = ws + 524288 + 65536;              // 2*4*512*16 = 65536
    float* d2 = ws + 524288 + 65536 + 65536;      // 2*4096 = 8192
    float* d3 = ws + 524288 + 65536 + 65536 + 8192;  // 128
    k_reduce <<<dim3(6144, 2),  256, 0, stream>>>(in, d1, p2, p3);
    k_combine<<<40, 256, 0, stream>>>(p2, p3, d2, d3);
    k_perm   <<<dim3(4096, 2),  256, 0, stream>>>(in, out);
    k_bcast  <<<dim3(12288, 2), 256, 0, stream>>>(d1, d2, d3, out);
}

// Round 5
// 182.514 us; speedup vs baseline: 1.2620x; 1.0254x over previous
//
#include <hip/hip_runtime.h>

// Layout facts (floats):
//   input  x: (2,4,4,4,1048576)  -> slice(b,i) base = b*67108864 + i*16777216
//   output  : (2, 4*262144, 64)  -> slice(b,i) base = b*67108864 + i*16777216
// float4 strides: batch 16777216, level 4194304.
//
// Tables are stored PRE-PERMUTED in the order k_bcast's lanes consume them:
//   d1p per batch: [zq:16][yh4:16][xh4:16][xl:4][yl:4] float4s, f4 = 4 z-subvals
//     -> bcast l1 block blk reads d1p[zq(blk)*4096 + yh4(blk)*256 + tid] (coalesced)
//   d2p per batch: [zq:4][yh2:4][xh2:4][xl:4][yl:4] float4s
//     -> bcast l2 block reads d2p[(zq*4+yh2)*64 + (tid&63)]
// Three dispatches:
//   D1 k_reduce   : l1/l2/l3 reductions, uniform 32KB pure-read blocks
//   D2 k_permcomb : level-0 permutation (8192 blks) + combine partials (40 blks)
//   D3 k_bcast    : uniform 16KB pure-write blocks; 1 coalesced table load each

typedef float f4 __attribute__((ext_vector_type(4)));

__global__ __launch_bounds__(256) void k_reduce(const float* __restrict__ in,
                                                float* __restrict__ d1,
                                                float* __restrict__ p2,
                                                float* __restrict__ p3) {
    const int b = blockIdx.y;
    const int bx = blockIdx.x;
    const int tid = threadIdx.x;
    __shared__ float red[64];
    const f4* in4 = (const f4*)in;

    if (bx < 2048) {
        // ---- level 1 reduce, split by k-pair (32KB read, exact partition) ----
        const int tlow = bx >> 1;            // y'*16 + z'/4
        const int kh = bx & 1;
        const long base4 = (long)b * 16777216 + 4194304;
        float acc[2] = {0.f, 0.f};
        for (int dz = 0; dz < 4; ++dz) {
            long rb = base4 + (long)(dz * 1024 + tlow) * 1024;
#pragma unroll
            for (int kk = 0; kk < 2; ++kk) {
                f4 v = __builtin_nontemporal_load(&in4[rb + (kh * 2 + kk) * 256 + tid]);
                acc[kk] += v.x + v.y + v.z + v.w;
            }
        }
#pragma unroll
        for (int kk = 0; kk < 2; ++kk) {     // reduce dx bits (tid 2..3)
            acc[kk] += __shfl_xor(acc[kk], 4);
            acc[kk] += __shfl_xor(acc[kk], 8);
        }
        if ((tid & 12) == 0) {
            int yp = tlow >> 4;
            int zp = ((tlow & 15) << 2) + (tid & 3);
#pragma unroll
            for (int kk = 0; kk < 2; ++kk) {
                int xp = (kh * 2 + kk) * 16 + (tid >> 4);
                int f4i = (zp >> 2) * 4096 + (yp >> 2) * 256 +
                          (xp >> 2) * 16 + (xp & 3) * 4 + (yp & 3);
                d1[b * 262144 + f4i * 4 + (zp & 3)] = acc[kk] * (1.0f / 64.0f);
            }
        }
    } else if (bx < 4096) {
        // ---- level 2 reduce partials, dz split into 8 groups of 2 (32KB) ----
        const int blk = bx - 2048;
        const int g = blk & 7, cell = blk >> 3;
        const int yp = cell >> 4, xp = cell & 15;
        const long base4 = (long)b * 16777216 + 2 * 4194304 + yp * 16384 + xp * 1024;
        float acc = 0.f;
        for (int dzi = 0; dzi < 2; ++dzi) {
            long rb = base4 + (long)(g * 2 + dzi) * 262144;
#pragma unroll
            for (int k = 0; k < 4; ++k) {
                f4 v = __builtin_nontemporal_load(&in4[rb + k * 256 + tid]);
                acc += v.x + v.y + v.z + v.w;   // z' = (tid>>2)&15
            }
        }
        acc += __shfl_xor(acc, 1);
        acc += __shfl_xor(acc, 2);
        if ((tid & 3) == 0) red[tid >> 2] = acc;
        __syncthreads();
        if (tid < 16) {
            float s = red[tid] + red[16 + tid] + red[32 + tid] + red[48 + tid];
            p2[(b * 8 + g) * 4096 + xp * 256 + yp * 16 + tid] = s;
        }
    } else {
        // ---- level 3 reduce partials, k split into 8 chunks of 8 (32KB) ----
        const int blk = bx - 4096;
        const int kc = blk & 7;
        const int orig = blk >> 3;           // x'(2b) hi(4b) dxg(2b)
        const int xp = orig >> 6, hi = (orig >> 2) & 15, dxg = orig & 3;
        const long base4 = (long)b * 16777216 + 3 * 4194304 +
                           (long)hi * 262144 + xp * 65536 + dxg * 16384;
        float acc = 0.f;                     // c = tid>>4 fixed per thread
        for (int kk = 0; kk < 8; ++kk) {
            f4 v = __builtin_nontemporal_load(&in4[base4 + (kc * 8 + kk) * 256 + tid]);
            acc += v.x + v.y + v.z + v.w;
        }
        acc += __shfl_xor(acc, 1);
        acc += __shfl_xor(acc, 2);
        acc += __shfl_xor(acc, 4);
        acc += __shfl_xor(acc, 8);
        if ((tid & 15) == 0) red[tid >> 4] = acc;
        __syncthreads();
        if (tid < 16) {
            int G = (hi * 4 + dxg) * 8 + kc;             // 0..511
            p3[((b * 4 + xp) * 512 + G) * 16 + tid] = red[tid];
        }
    }
}

__global__ __launch_bounds__(256) void k_permcomb(const float* __restrict__ in,
                                                  float* __restrict__ out,
                                                  const float* __restrict__ p2,
                                                  const float* __restrict__ p3,
                                                  float* __restrict__ d2,
                                                  float* __restrict__ d3) {
    const int bx = blockIdx.x;
    const int tid = threadIdx.x;
    __shared__ float smem[16 * 260];

    if (bx < 8192) {
        // ---- level 0: pure permutation via LDS tile ----
        const int b = bx >> 12;
        const int rem = bx & 4095;
        const int Y_hi = rem >> 6, Z_hi = rem & 63;
        const f4* in4 = (const f4*)in;
        f4* out4 = (f4*)out;
        const long in_b4 = (long)b * 16777216;
#pragma unroll
        for (int k = 0; k < 4; ++k) {
            int idx = k * 256 + tid;
            int r = idx >> 6;
            int col4 = idx & 63;
            int Y = Y_hi * 4 + (r >> 2), Z = Z_hi * 4 + (r & 3);
            f4 v = __builtin_nontemporal_load(&in4[in_b4 + (long)Y * 16384 + Z * 64 + col4]);
            *(f4*)&smem[r * 260 + col4 * 4] = v;
        }
        __syncthreads();
        const long out_b4 = (long)b * 16777216 + (long)Z_hi * 65536 + Y_hi * 1024;
#pragma unroll
        for (int k = 0; k < 4; ++k) {
            int idx = k * 256 + tid;
            int X = ((idx >> 4) << 2) + ((tid >> 2) & 3);
            int row0 = (tid & 3) * 4;
            f4 v;
            v.x = smem[(row0 + 0) * 260 + X];
            v.y = smem[(row0 + 1) * 260 + X];
            v.z = smem[(row0 + 2) * 260 + X];
            v.w = smem[(row0 + 3) * 260 + X];
            __builtin_nontemporal_store(v, &out4[out_b4 + idx]);
        }
    } else if (bx < 8224) {
        // ---- combine p2 -> d2p (new layout) ----
        int idx = (bx - 8192) * 256 + tid;
        int b = idx >> 12, r = idx & 4095;
        int xp = r >> 8, yp = (r >> 4) & 15, zp = r & 15;
        float s = 0.f;
#pragma unroll
        for (int g = 0; g < 8; ++g) s += p2[(b * 8 + g) * 4096 + r];
        int f4i = (zp >> 2) * 256 + (yp >> 2) * 64 + (xp >> 2) * 16 + (xp & 3) * 4 + (yp & 3);
        d2[b * 4096 + f4i * 4 + (zp & 3)] = s * (1.0f / 4096.0f);
    } else {
        // ---- combine p3 -> d3 ----
        int v = bx - 8224;                   // 0..7
        int b = v >> 2, xp = v & 3;
        int c = tid & 15, gp = tid >> 4;
        const float* pb = p3 + (long)((b * 4 + xp) * 512) * 16 + c;
        float s = 0.f;
#pragma unroll
        for (int j = 0; j < 32; ++j) s += pb[(gp * 32 + j) * 16];
        float* red = smem;
        red[gp * 16 + c] = s;
        __syncthreads();
        if (tid < 16) {
            float t = 0.f;
#pragma unroll
            for (int g = 0; g < 16; ++g) t += red[g * 16 + tid];
            d3[b * 64 + xp * 16 + tid] = t * (1.0f / 262144.0f);
        }
    }
}

__global__ __launch_bounds__(256) void k_bcast(const float* __restrict__ d1,
                                               const float* __restrict__ d2,
                                               const float* __restrict__ d3,
                                               float* __restrict__ out) {
    const int b = blockIdx.y;
    const int bx = blockIdx.x;
    const int tid = threadIdx.x;
    f4* out4 = (f4*)out;

    if (bx < 4096) {
        // ---- level 1 broadcast: one coalesced 4KB table read per block ----
        const f4* d14 = (const f4*)d1;
        const f4 v = d14[b * 65536 + ((bx >> 6) & 15) * 4096 + (bx & 15) * 256 + tid];
        const long ob = (long)b * 16777216 + 4194304;
#pragma unroll
        for (int k = 0; k < 4; ++k)
            __builtin_nontemporal_store(v, &out4[ob + bx * 1024 + k * 256 + tid]);
    } else if (bx < 8192) {
        // ---- level 2 broadcast: one coalesced 1KB table read per block ----
        const int blk = bx - 4096;
        const f4* d24 = (const f4*)d2;
        const f4 v = d24[b * 1024 + ((blk >> 6) & 3) * 256 + (blk & 3) * 64 + (tid & 63)];
        const long ob = (long)b * 16777216 + 2 * 4194304;
#pragma unroll
        for (int k = 0; k < 4; ++k)
            __builtin_nontemporal_store(v, &out4[ob + blk * 1024 + k * 256 + tid]);
    } else {
        // ---- level 3 broadcast: same 64-float row everywhere ----
        const int blk = bx - 8192;
        const f4* d34 = (const f4*)d3;
        const f4 v = d34[b * 16 + (tid & 15)];
        const long ob = (long)b * 16777216 + 3 * 4194304;
#pragma unroll
        for (int k = 0; k < 4; ++k)
            __builtin_nontemporal_store(v, &out4[ob + blk * 1024 + k * 256 + tid]);
    }
}

extern "C" void kernel_launch(void* const* d_in, const int* in_sizes, int n_in,
                              void* d_out, int out_size, void* d_ws, size_t ws_size,
                              hipStream_t stream) {
    const float* in = (const float*)d_in[0];
    float* out = (float*)d_out;
    float* ws = (float*)d_ws;
    float* d1 = ws;                               // 2*262144 = 524288 floats
    float* p2 = ws + 524288;                      // 2*8*4096 = 65536
    float* p3 = ws + 524288 + 65536;              // 2*4*512*16 = 65536
    float* d2 = ws + 524288 + 65536 + 65536;      // 2*4096 = 8192
    float* d3 = ws + 524288 + 65536 + 65536 + 8192;  // 128
    k_reduce  <<<dim3(6144, 2),  256, 0, stream>>>(in, d1, p2, p3);
    k_permcomb<<<dim3(8232),     256, 0, stream>>>(in, out, p2, p3, d2, d3);
    k_bcast   <<<dim3(12288, 2), 256, 0, stream>>>(d1, d2, d3, out);
}

// Round 6
// 181.441 us; speedup vs baseline: 1.2694x; 1.0059x over previous
//
#include <hip/hip_runtime.h>

// Layout facts (floats):
//   input  x: (2,4,4,4,1048576)  -> slice(b,i) base = b*67108864 + i*16777216
//   output  : (2, 4*262144, 64)  -> slice(b,i) base = b*67108864 + i*16777216
// float4 strides: batch 16777216, level 4194304.
//
// Tables are stored PRE-PERMUTED in the order k_bcast's lanes consume them:
//   d1p per batch: [zq:16][yh4:16][xh4:16][xl:4][yl:4] float4s, f4 = 4 z-subvals
//   d2p per batch: [zq:4][yh2:4][xh2:4][xl:4][yl:4] float4s
// Three direction-pure dispatches (uniform, coarse blocks):
//   D1 k_reduce   : l1/l2/l3 reductions, 64KB pure-read blocks (3072 x 2)
//   D2 k_permcomb : level-0 permutation (8192) + combine partials (40)
//   D3 k_bcast    : 32KB pure-write blocks (6144 x 2); coalesced table reads

typedef float f4 __attribute__((ext_vector_type(4)));

__global__ __launch_bounds__(256) void k_reduce(const float* __restrict__ in,
                                                float* __restrict__ d1,
                                                float* __restrict__ p2,
                                                float* __restrict__ p3) {
    const int b = blockIdx.y;
    const int bx = blockIdx.x;
    const int tid = threadIdx.x;
    __shared__ float red[64];
    const f4* in4 = (const f4*)in;

    if (bx < 1024) {
        // ---- level 1 reduce: block per tlow = y'*16 + z'/4, 64KB read ----
        const int tlow = bx;
        const long base4 = (long)b * 16777216 + 4194304;
        float acc[4] = {0.f, 0.f, 0.f, 0.f};
        for (int dz = 0; dz < 4; ++dz) {
            long rb = base4 + (long)(dz * 1024 + tlow) * 1024;
#pragma unroll
            for (int k = 0; k < 4; ++k) {
                f4 v = __builtin_nontemporal_load(&in4[rb + k * 256 + tid]);
                acc[k] += v.x + v.y + v.z + v.w;
            }
        }
#pragma unroll
        for (int k = 0; k < 4; ++k) {        // reduce dx bits (tid 2..3)
            acc[k] += __shfl_xor(acc[k], 4);
            acc[k] += __shfl_xor(acc[k], 8);
        }
        if ((tid & 12) == 0) {
            int yp = tlow >> 4;
            int zp = ((tlow & 15) << 2) + (tid & 3);
#pragma unroll
            for (int k = 0; k < 4; ++k) {
                int xp = k * 16 + (tid >> 4);
                int f4i = (zp >> 2) * 4096 + (yp >> 2) * 256 +
                          (xp >> 2) * 16 + (xp & 3) * 4 + (yp & 3);
                d1[b * 262144 + f4i * 4 + (zp & 3)] = acc[k] * (1.0f / 64.0f);
            }
        }
    } else if (bx < 2048) {
        // ---- level 2 reduce partials: 4 dz per block (64KB) ----
        const int blk = bx - 1024;
        const int g = blk & 3, cell = blk >> 2;
        const int yp = cell >> 4, xp = cell & 15;
        const long base4 = (long)b * 16777216 + 2 * 4194304 + yp * 16384 + xp * 1024;
        float acc = 0.f;
        for (int dzi = 0; dzi < 4; ++dzi) {
            long rb = base4 + (long)(g * 4 + dzi) * 262144;
#pragma unroll
            for (int k = 0; k < 4; ++k) {
                f4 v = __builtin_nontemporal_load(&in4[rb + k * 256 + tid]);
                acc += v.x + v.y + v.z + v.w;   // z' = (tid>>2)&15
            }
        }
        acc += __shfl_xor(acc, 1);
        acc += __shfl_xor(acc, 2);
        if ((tid & 3) == 0) red[tid >> 2] = acc;
        __syncthreads();
        if (tid < 16) {
            float s = red[tid] + red[16 + tid] + red[32 + tid] + red[48 + tid];
            p2[(b * 4 + g) * 4096 + xp * 256 + yp * 16 + tid] = s;
        }
    } else {
        // ---- level 3 reduce partials: 16 k-chunks per block (64KB) ----
        const int blk = bx - 2048;
        const int kc = blk & 3;
        const int orig = blk >> 2;           // x'(2b) hi(4b) dxg(2b)
        const int xp = orig >> 6, hi = (orig >> 2) & 15, dxg = orig & 3;
        const long base4 = (long)b * 16777216 + 3 * 4194304 +
                           (long)hi * 262144 + xp * 65536 + dxg * 16384;
        float acc = 0.f;                     // c = tid>>4 fixed per thread
        for (int kk = 0; kk < 16; ++kk) {
            f4 v = __builtin_nontemporal_load(&in4[base4 + (kc * 16 + kk) * 256 + tid]);
            acc += v.x + v.y + v.z + v.w;
        }
        acc += __shfl_xor(acc, 1);
        acc += __shfl_xor(acc, 2);
        acc += __shfl_xor(acc, 4);
        acc += __shfl_xor(acc, 8);
        if ((tid & 15) == 0) red[tid >> 4] = acc;
        __syncthreads();
        if (tid < 16) {
            int G = (hi * 4 + dxg) * 4 + kc;             // 0..255
            p3[((b * 4 + xp) * 256 + G) * 16 + tid] = red[tid];
        }
    }
}

__global__ __launch_bounds__(256) void k_permcomb(const float* __restrict__ in,
                                                  float* __restrict__ out,
                                                  const float* __restrict__ p2,
                                                  const float* __restrict__ p3,
                                                  float* __restrict__ d2,
                                                  float* __restrict__ d3) {
    const int bx = blockIdx.x;
    const int tid = threadIdx.x;
    __shared__ float smem[16 * 260];

    if (bx < 8192) {
        // ---- level 0: pure permutation via LDS tile ----
        const int b = bx >> 12;
        const int rem = bx & 4095;
        const int Y_hi = rem >> 6, Z_hi = rem & 63;
        const f4* in4 = (const f4*)in;
        f4* out4 = (f4*)out;
        const long in_b4 = (long)b * 16777216;
#pragma unroll
        for (int k = 0; k < 4; ++k) {
            int idx = k * 256 + tid;
            int r = idx >> 6;
            int col4 = idx & 63;
            int Y = Y_hi * 4 + (r >> 2), Z = Z_hi * 4 + (r & 3);
            f4 v = __builtin_nontemporal_load(&in4[in_b4 + (long)Y * 16384 + Z * 64 + col4]);
            *(f4*)&smem[r * 260 + col4 * 4] = v;
        }
        __syncthreads();
        const long out_b4 = (long)b * 16777216 + (long)Z_hi * 65536 + Y_hi * 1024;
#pragma unroll
        for (int k = 0; k < 4; ++k) {
            int idx = k * 256 + tid;
            int X = ((idx >> 4) << 2) + ((tid >> 2) & 3);
            int row0 = (tid & 3) * 4;
            f4 v;
            v.x = smem[(row0 + 0) * 260 + X];
            v.y = smem[(row0 + 1) * 260 + X];
            v.z = smem[(row0 + 2) * 260 + X];
            v.w = smem[(row0 + 3) * 260 + X];
            __builtin_nontemporal_store(v, &out4[out_b4 + idx]);
        }
    } else if (bx < 8224) {
        // ---- combine p2 -> d2p ----
        int idx = (bx - 8192) * 256 + tid;
        int b = idx >> 12, r = idx & 4095;
        int xp = r >> 8, yp = (r >> 4) & 15, zp = r & 15;
        float s = 0.f;
#pragma unroll
        for (int g = 0; g < 4; ++g) s += p2[(b * 4 + g) * 4096 + r];
        int f4i = (zp >> 2) * 256 + (yp >> 2) * 64 + (xp >> 2) * 16 + (xp & 3) * 4 + (yp & 3);
        d2[b * 4096 + f4i * 4 + (zp & 3)] = s * (1.0f / 4096.0f);
    } else {
        // ---- combine p3 -> d3 ----
        int v = bx - 8224;                   // 0..7
        int b = v >> 2, xp = v & 3;
        int c = tid & 15, gp = tid >> 4;
        const float* pb = p3 + (long)((b * 4 + xp) * 256) * 16 + c;
        float s = 0.f;
#pragma unroll
        for (int j = 0; j < 16; ++j) s += pb[(gp * 16 + j) * 16];
        float* red = smem;
        red[gp * 16 + c] = s;
        __syncthreads();
        if (tid < 16) {
            float t = 0.f;
#pragma unroll
            for (int g = 0; g < 16; ++g) t += red[g * 16 + tid];
            d3[b * 64 + xp * 16 + tid] = t * (1.0f / 262144.0f);
        }
    }
}

__global__ __launch_bounds__(256) void k_bcast(const float* __restrict__ d1,
                                               const float* __restrict__ d2,
                                               const float* __restrict__ d3,
                                               float* __restrict__ out) {
    const int b = blockIdx.y;
    const int bx = blockIdx.x;
    const int tid = threadIdx.x;
    f4* out4 = (f4*)out;

    if (bx < 2048) {
        // ---- level 1 broadcast: two coalesced 4KB table rows per block ----
        const f4* d14 = (const f4*)d1;
        const int bx0 = bx * 2;
        const int base = b * 65536 + ((bx0 >> 6) & 15) * 4096 + (bx0 & 15) * 256 + tid;
        const f4 v0 = d14[base];
        const f4 v1 = d14[base + 256];
        const long ob = (long)b * 16777216 + 4194304 + (long)bx * 2048;
#pragma unroll
        for (int j = 0; j < 8; ++j)
            __builtin_nontemporal_store((j < 4) ? v0 : v1, &out4[ob + j * 256 + tid]);
    } else if (bx < 4096) {
        // ---- level 2 broadcast: two coalesced 1KB table rows per block ----
        const int blk = bx - 2048;
        const f4* d24 = (const f4*)d2;
        const int bx0 = blk * 2;
        const int base = b * 1024 + ((bx0 >> 6) & 3) * 256 + (bx0 & 3) * 64 + (tid & 63);
        const f4 v0 = d24[base];
        const f4 v1 = d24[base + 64];
        const long ob = (long)b * 16777216 + 2 * 4194304 + (long)blk * 2048;
#pragma unroll
        for (int j = 0; j < 8; ++j)
            __builtin_nontemporal_store((j < 4) ? v0 : v1, &out4[ob + j * 256 + tid]);
    } else {
        // ---- level 3 broadcast: same 64-float row everywhere ----
        const int blk = bx - 4096;
        const f4* d34 = (const f4*)d3;
        const f4 v = d34[b * 16 + (tid & 15)];
        const long ob = (long)b * 16777216 + 3 * 4194304 + (long)blk * 2048;
#pragma unroll
        for (int j = 0; j < 8; ++j)
            __builtin_nontemporal_store(v, &out4[ob + j * 256 + tid]);
    }
}

extern "C" void kernel_launch(void* const* d_in, const int* in_sizes, int n_in,
                              void* d_out, int out_size, void* d_ws, size_t ws_size,
                              hipStream_t stream) {
    const float* in = (const float*)d_in[0];
    float* out = (float*)d_out;
    float* ws = (float*)d_ws;
    float* d1 = ws;                               // 2*262144 = 524288 floats
    float* p2 = ws + 524288;                      // 2*4*4096 = 32768
    float* p3 = ws + 524288 + 65536;              // 2*4*256*16 = 32768
    float* d2 = ws + 524288 + 65536 + 65536;      // 2*4096 = 8192
    float* d3 = ws + 524288 + 65536 + 65536 + 8192;  // 128
    k_reduce  <<<dim3(3072, 2), 256, 0, stream>>>(in, d1, p2, p3);
    k_permcomb<<<dim3(8232),    256, 0, stream>>>(in, out, p2, p3, d2, d3);
    k_bcast   <<<dim3(6144, 2), 256, 0, stream>>>(d1, d2, d3, out);
}